// Round 1
// baseline (515.737 us; speedup 1.0000x reference)
//
#include <hip/hip_runtime.h>
#include <hip/hip_cooperative_groups.h>

namespace cg = cooperative_groups;

// Problem constants (fixed by the reference).
#define T_LEN 4096
#define B_SZ  2
#define H_SZ  2048
#define NM    8            // N2 complex modes
#define BH    (B_SZ * H_SZ)

// ---------------------------------------------------------------------------
// S4D via chunked linear recurrence (exact equivalent of the FFT conv):
//   S_n(t) = w_n * S_n(t-1) + x(t),  w_n = exp(dt*A_n)
//   out(t) = 2*Re( sum_n Cd_n * S_n(t) ) + D*x(t),  Cd = C*(w-1)/A
//
// Round 6: single cooperative kernel, 2 grid.sync()s.
//  - kills 2 dispatch gaps + k2's half-idle standalone dispatch
//  - w-table computed once, lives in regs across both syncs
//  - C=32 (LC=128): 512 blocks x 256 thr -> needs only 2 blocks/CU
//    co-resident vs 4/CU capacity at the 128-VGPR cap (2x margin, coop
//    launch can't fail on occupancy); states = 8.4 MB (L2-resident)
//  - BT=16 prefetch depth: 4 KB in flight/wave compensates for the
//    halved wave count (8 waves/CU) in the memory-bound phases
//  - guarded fallback to the proven 3-kernel path if coop launch errors
// ---------------------------------------------------------------------------

template <int C, int LC, int BT>
__global__ void __launch_bounds__(256, 4)
s4d_fused(const float* __restrict__ x,
          const float* __restrict__ Dp,
          const float* __restrict__ log_dt,
          const float* __restrict__ Arl,
          const float* __restrict__ Aimp,
          const float* __restrict__ Crep,
          const float* __restrict__ Cimp,
          float2* __restrict__ states,
          float* __restrict__ out) {
    cg::grid_group grid = cg::this_grid();

    const int g = blockIdx.x * blockDim.x + threadIdx.x;   // [C * BH)
    const int h = g % H_SZ;
    const int b = (g / H_SZ) % B_SZ;
    const int c = g / BH;

    const float dt = __expf(log_dt[h]);
    float wr[NM], wi[NM];
#pragma unroll
    for (int n = 0; n < NM; ++n) {
        float ar  = -__expf(Arl[h * NM + n]);
        float ai  = Aimp[h * NM + n];
        float er  = __expf(ar * dt);
        float ang = ai * dt;
        wr[n] = er * __cosf(ang);
        wi[n] = er * __sinf(ang);
    }

    // ---- Phase 1: chunk-local end state -----------------------------------
    {
        float sr[NM], si[NM];
#pragma unroll
        for (int n = 0; n < NM; ++n) { sr[n] = 0.f; si[n] = 0.f; }

        const float* xp = x + (size_t)c * LC * BH + b * H_SZ + h;
        float buf[BT], nxt[BT];
#pragma unroll
        for (int i = 0; i < BT; ++i) buf[i] = xp[(size_t)i * BH];

#pragma unroll
        for (int tb = 0; tb < LC / BT; ++tb) {
            if (tb + 1 < LC / BT) {
#pragma unroll
                for (int i = 0; i < BT; ++i)
                    nxt[i] = xp[(size_t)((tb + 1) * BT + i) * BH];
            }
#pragma unroll
            for (int i = 0; i < BT; ++i) {
                float xv = buf[i];
#pragma unroll
                for (int n = 0; n < NM; ++n) {
                    float nsr = fmaf(wr[n], sr[n], fmaf(-wi[n], si[n], xv));
                    float nsi = fmaf(wr[n], si[n], wi[n] * sr[n]);
                    sr[n] = nsr; si[n] = nsi;
                }
            }
#pragma unroll
            for (int i = 0; i < BT; ++i) buf[i] = nxt[i];
        }

        float2* st = states + (size_t)(c * B_SZ + b) * NM * H_SZ + h;
#pragma unroll
        for (int n = 0; n < NM; ++n)
            st[(size_t)n * H_SZ] = make_float2(sr[n], si[n]);
    }

    __threadfence();
    grid.sync();
    __threadfence();

    // ---- Phase 2: exclusive carry scan over chunks (first BH*NM threads) --
    if (g < BH * NM) {
        const int h2 = g % H_SZ;
        const int n2 = (g / H_SZ) % NM;
        const int b2 = g / (H_SZ * NM);

        float dt2 = __expf(log_dt[h2]);
        float Are = -__expf(Arl[h2 * NM + n2]);
        float Aim = Aimp[h2 * NM + n2];
        float er  = __expf(Are * dt2 * (float)LC);   // w^LC
        float ang = Aim * dt2 * (float)LC;
        float cwr = er * __cosf(ang), cwi = er * __sinf(ang);

        const size_t stride = (size_t)B_SZ * NM * H_SZ;
        float2* base = states + ((size_t)b2 * NM + n2) * H_SZ + h2;

        float2 v[C];
#pragma unroll
        for (int i = 0; i < C; ++i) v[i] = base[(size_t)i * stride];

        float cr = 0.f, ci = 0.f;
#pragma unroll
        for (int i = 0; i < C; ++i) {
            base[(size_t)i * stride] = make_float2(cr, ci);
            float ncr = fmaf(cwr, cr, fmaf(-cwi, ci, v[i].x));
            float nci = fmaf(cwr, ci, fmaf(cwi, cr, v[i].y));
            cr = ncr; ci = nci;
        }
    }

    __threadfence();
    grid.sync();
    __threadfence();

    // ---- Phase 3: rescan with carry-in, emit output -----------------------
    {
        float cdr[NM], cdi[NM];
#pragma unroll
        for (int n = 0; n < NM; ++n) {
            float ar  = -__expf(Arl[h * NM + n]);
            float ai  = Aimp[h * NM + n];
            // Cd = (Cre + i*Cim) * (w - 1) / A   (divide via conj(A)/|A|^2)
            float inv = 1.0f / (ar * ar + ai * ai);
            float tr = ((wr[n] - 1.f) * ar + wi[n] * ai) * inv;
            float ti = (wi[n] * ar - (wr[n] - 1.f) * ai) * inv;
            float Cre = Crep[h * NM + n], Cim = Cimp[h * NM + n];
            cdr[n] = Cre * tr - Cim * ti;
            cdi[n] = Cre * ti + Cim * tr;
        }

        const float2* st = states + (size_t)(c * B_SZ + b) * NM * H_SZ + h;
        float sr[NM], si[NM];
#pragma unroll
        for (int n = 0; n < NM; ++n) {
            float2 v2 = st[(size_t)n * H_SZ];
            sr[n] = v2.x; si[n] = v2.y;
        }

        float Dv = Dp[h];
        const float* xp = x + (size_t)c * LC * BH + b * H_SZ + h;
        float* op = out + (size_t)c * LC * BH + b * H_SZ + h;

        float buf[BT], nxt[BT];
#pragma unroll
        for (int i = 0; i < BT; ++i) buf[i] = xp[(size_t)i * BH];

#pragma unroll
        for (int tb = 0; tb < LC / BT; ++tb) {
            if (tb + 1 < LC / BT) {
#pragma unroll
                for (int i = 0; i < BT; ++i)
                    nxt[i] = xp[(size_t)((tb + 1) * BT + i) * BH];
            }
#pragma unroll
            for (int i = 0; i < BT; ++i) {
                float xv = buf[i];
                float y = 0.f;
#pragma unroll
                for (int n = 0; n < NM; ++n) {
                    float nsr = fmaf(wr[n], sr[n], fmaf(-wi[n], si[n], xv));
                    float nsi = fmaf(wr[n], si[n], wi[n] * sr[n]);
                    sr[n] = nsr; si[n] = nsi;
                    y = fmaf(cdr[n], nsr, y);
                    y = fmaf(-cdi[n], nsi, y);
                }
                __builtin_nontemporal_store(fmaf(Dv, xv, 2.0f * y),
                                            op + (size_t)(tb * BT + i) * BH);
            }
#pragma unroll
            for (int i = 0; i < BT; ++i) buf[i] = nxt[i];
        }
    }
}

// ---------------------------------------------------------------------------
// Fallback: the proven round-5 3-kernel path (used only if cooperative
// launch is rejected, e.g. unsupported under graph capture).
// ---------------------------------------------------------------------------

template <int LC>
__global__ void __launch_bounds__(256, 4)
k1_chunk_end(const float* __restrict__ x,
             const float* __restrict__ log_dt,
             const float* __restrict__ Arl,
             const float* __restrict__ Aimp,
             float2* __restrict__ states) {
    int g = blockIdx.x * blockDim.x + threadIdx.x;
    int h = g % H_SZ;
    int b = (g / H_SZ) % B_SZ;
    int c = g / BH;

    float dt = __expf(log_dt[h]);
    float wr[NM], wi[NM];
#pragma unroll
    for (int n = 0; n < NM; ++n) {
        float ar  = -__expf(Arl[h * NM + n]);
        float ai  = Aimp[h * NM + n];
        float er  = __expf(ar * dt);
        float ang = ai * dt;
        wr[n] = er * __cosf(ang);
        wi[n] = er * __sinf(ang);
    }

    float sr[NM], si[NM];
#pragma unroll
    for (int n = 0; n < NM; ++n) { sr[n] = 0.f; si[n] = 0.f; }

    const float* xp = x + (size_t)c * LC * BH + b * H_SZ + h;

    constexpr int BT = 8;
    float buf[BT], nxt[BT];
#pragma unroll
    for (int i = 0; i < BT; ++i) buf[i] = xp[(size_t)i * BH];

#pragma unroll
    for (int tb = 0; tb < LC / BT; ++tb) {
        if (tb + 1 < LC / BT) {
#pragma unroll
            for (int i = 0; i < BT; ++i)
                nxt[i] = xp[(size_t)((tb + 1) * BT + i) * BH];
        }
#pragma unroll
        for (int i = 0; i < BT; ++i) {
            float xv = buf[i];
#pragma unroll
            for (int n = 0; n < NM; ++n) {
                float nsr = fmaf(wr[n], sr[n], fmaf(-wi[n], si[n], xv));
                float nsi = fmaf(wr[n], si[n], wi[n] * sr[n]);
                sr[n] = nsr; si[n] = nsi;
            }
        }
#pragma unroll
        for (int i = 0; i < BT; ++i) buf[i] = nxt[i];
    }

    float2* st = states + (size_t)(c * B_SZ + b) * NM * H_SZ + h;
#pragma unroll
    for (int n = 0; n < NM; ++n) st[(size_t)n * H_SZ] = make_float2(sr[n], si[n]);
}

template <int CC, int LC>
__global__ void __launch_bounds__(256, 4)
k2_carry_scan(const float* __restrict__ log_dt,
              const float* __restrict__ Arl,
              const float* __restrict__ Aimp,
              float2* __restrict__ states) {
    int g = blockIdx.x * blockDim.x + threadIdx.x;
    int h = g % H_SZ;
    int n = (g / H_SZ) % NM;
    int b = g / (H_SZ * NM);

    float dt  = __expf(log_dt[h]);
    float Are = -__expf(Arl[h * NM + n]);
    float Aim = Aimp[h * NM + n];
    float er  = __expf(Are * dt * (float)LC);
    float ang = Aim * dt * (float)LC;
    float wr = er * __cosf(ang), wi = er * __sinf(ang);

    const size_t stride = (size_t)B_SZ * NM * H_SZ;
    float2* base = states + ((size_t)b * NM + n) * H_SZ + h;

    float cr = 0.f, ci = 0.f;
    constexpr int BT = 8;
    float2 buf[BT], nxt[BT];
#pragma unroll
    for (int i = 0; i < BT; ++i) buf[i] = base[(size_t)i * stride];

#pragma unroll
    for (int cb = 0; cb < CC / BT; ++cb) {
        if (cb + 1 < CC / BT) {
#pragma unroll
            for (int i = 0; i < BT; ++i)
                nxt[i] = base[(size_t)((cb + 1) * BT + i) * stride];
        }
#pragma unroll
        for (int i = 0; i < BT; ++i) {
            int c = cb * BT + i;
            base[(size_t)c * stride] = make_float2(cr, ci);
            float ncr = fmaf(wr, cr, fmaf(-wi, ci, buf[i].x));
            float nci = fmaf(wr, ci, fmaf(wi, cr, buf[i].y));
            cr = ncr; ci = nci;
        }
#pragma unroll
        for (int i = 0; i < BT; ++i) buf[i] = nxt[i];
    }
}

template <int LC>
__global__ void __launch_bounds__(256, 4)
k3_output(const float* __restrict__ x,
          const float* __restrict__ Dp,
          const float* __restrict__ log_dt,
          const float* __restrict__ Arl,
          const float* __restrict__ Aimp,
          const float* __restrict__ Crep,
          const float* __restrict__ Cimp,
          const float2* __restrict__ states,
          float* __restrict__ out) {
    int g = blockIdx.x * blockDim.x + threadIdx.x;
    int h = g % H_SZ;
    int b = (g / H_SZ) % B_SZ;
    int c = g / BH;

    float dt = __expf(log_dt[h]);
    float wr[NM], wi[NM], cdr[NM], cdi[NM];
#pragma unroll
    for (int n = 0; n < NM; ++n) {
        float ar  = -__expf(Arl[h * NM + n]);
        float ai  = Aimp[h * NM + n];
        float er  = __expf(ar * dt);
        float ang = ai * dt;
        float wrn = er * __cosf(ang);
        float win = er * __sinf(ang);
        wr[n] = wrn; wi[n] = win;
        float inv = 1.0f / (ar * ar + ai * ai);
        float tr = ((wrn - 1.f) * ar + win * ai) * inv;
        float ti = (win * ar - (wrn - 1.f) * ai) * inv;
        float Cre = Crep[h * NM + n], Cim = Cimp[h * NM + n];
        cdr[n] = Cre * tr - Cim * ti;
        cdi[n] = Cre * ti + Cim * tr;
    }

    const float2* st = states + (size_t)(c * B_SZ + b) * NM * H_SZ + h;
    float sr[NM], si[NM];
#pragma unroll
    for (int n = 0; n < NM; ++n) {
        float2 v = st[(size_t)n * H_SZ];
        sr[n] = v.x; si[n] = v.y;
    }

    float Dv = Dp[h];
    const float* xp = x + (size_t)c * LC * BH + b * H_SZ + h;
    float* op = out + (size_t)c * LC * BH + b * H_SZ + h;

    constexpr int BT = 8;
    float buf[BT], nxt[BT];
#pragma unroll
    for (int i = 0; i < BT; ++i) buf[i] = xp[(size_t)i * BH];

#pragma unroll
    for (int tb = 0; tb < LC / BT; ++tb) {
        if (tb + 1 < LC / BT) {
#pragma unroll
            for (int i = 0; i < BT; ++i)
                nxt[i] = xp[(size_t)((tb + 1) * BT + i) * BH];
        }
#pragma unroll
        for (int i = 0; i < BT; ++i) {
            float xv = buf[i];
            float y = 0.f;
#pragma unroll
            for (int n = 0; n < NM; ++n) {
                float nsr = fmaf(wr[n], sr[n], fmaf(-wi[n], si[n], xv));
                float nsi = fmaf(wr[n], si[n], wi[n] * sr[n]);
                sr[n] = nsr; si[n] = nsi;
                y = fmaf(cdr[n], nsr, y);
                y = fmaf(-cdi[n], nsi, y);
            }
            float ov = fmaf(Dv, xv, 2.0f * y);
            __builtin_nontemporal_store(ov, op + (size_t)(tb * BT + i) * BH);
        }
#pragma unroll
        for (int i = 0; i < BT; ++i) buf[i] = nxt[i];
    }
}

extern "C" void kernel_launch(void* const* d_in, const int* in_sizes, int n_in,
                              void* d_out, int out_size, void* d_ws, size_t ws_size,
                              hipStream_t stream) {
    const float* x      = (const float*)d_in[0];
    const float* Dp     = (const float*)d_in[1];
    const float* log_dt = (const float*)d_in[2];
    const float* Arl    = (const float*)d_in[3];
    const float* Aimp   = (const float*)d_in[4];
    const float* Cre    = (const float*)d_in[5];
    const float* Cim    = (const float*)d_in[6];
    float* out = (float*)d_out;
    float2* states = (float2*)d_ws;

    constexpr int C  = 32;
    constexpr int LC = T_LEN / C;        // 128
    constexpr int BT = 16;
    const size_t need = (size_t)C * BH * NM * sizeof(float2);   // 8.4 MB

    bool fused_ok = false;
    if (ws_size >= need) {
        int blocks = C * BH / 256;       // 512 blocks (2/CU co-resident, 2x margin)
        void* args[] = {(void*)&x, (void*)&Dp, (void*)&log_dt, (void*)&Arl,
                        (void*)&Aimp, (void*)&Cre, (void*)&Cim,
                        (void*)&states, (void*)&out};
        hipError_t e = hipLaunchCooperativeKernel(
            reinterpret_cast<void*>(&s4d_fused<C, LC, BT>),
            dim3(blocks), dim3(256), args, 0, stream);
        fused_ok = (e == hipSuccess);
        if (!fused_ok) (void)hipGetLastError();   // clear sticky error
    }

    if (!fused_ok) {
        // Proven round-5 3-kernel path.
        const size_t need64 = (size_t)64 * BH * NM * sizeof(float2);
        if (ws_size >= need64) {
            constexpr int Cf = 64, LCf = T_LEN / 64;
            int total1 = Cf * BH;
            k1_chunk_end<LCf><<<total1 / 256, 256, 0, stream>>>(x, log_dt, Arl, Aimp, states);
            int total2 = BH * NM;
            k2_carry_scan<Cf, LCf><<<total2 / 256, 256, 0, stream>>>(log_dt, Arl, Aimp, states);
            k3_output<LCf><<<total1 / 256, 256, 0, stream>>>(x, Dp, log_dt, Arl, Aimp,
                                                             Cre, Cim, states, out);
        } else {
            constexpr int Cf = 32, LCf = T_LEN / 32;
            int total1 = Cf * BH;
            k1_chunk_end<LCf><<<total1 / 256, 256, 0, stream>>>(x, log_dt, Arl, Aimp, states);
            int total2 = BH * NM;
            k2_carry_scan<Cf, LCf><<<total2 / 256, 256, 0, stream>>>(log_dt, Arl, Aimp, states);
            k3_output<LCf><<<total1 / 256, 256, 0, stream>>>(x, Dp, log_dt, Arl, Aimp,
                                                             Cre, Cim, states, out);
        }
    }
}

// Round 5
// 152.102 us; speedup vs baseline: 3.3907x; 3.3907x over previous
//
#include <hip/hip_runtime.h>

// Problem constants (fixed by the reference).
#define T_LEN 4096
#define B_SZ  2
#define H_SZ  2048
#define NM    8            // N2 complex modes
#define BH    (B_SZ * H_SZ)

// ---------------------------------------------------------------------------
// S4D via chunked linear recurrence (exact equivalent of the FFT conv):
//   S_n(t) = w_n * S_n(t-1) + x(t),  w_n = exp(dt*A_n)
//   out(t) = 2*Re( sum_n Cd_n * S_n(t) ) + D*x(t),  Cd = C*(w-1)/A
//
// Round 6 post-mortem: cooperative fusion spilled (cg grid.sync is a real
// call on ROCm -> everything live across it went to scratch: VGPR=64,
// +110 MB writes, 445 us). Reverted to the proven 3-kernel path.
// Round 7: k2 re-gridded 128 blocks x 256 thr -> 256 blocks x 128 thr so
// every CU hosts carry-scan work (was half-chip), BT=16 prefetch to cover
// cross-XCD L2/L3 latency on the stride-256KB chunk walk.
// k1/k3 unchanged from the 151.7 us version.
// (Rounds 8-10: resubmits — GPUAcquisitionTimeout, no data.)
// ---------------------------------------------------------------------------

template <int LC>
__global__ void __launch_bounds__(256, 4)
k1_chunk_end(const float* __restrict__ x,
             const float* __restrict__ log_dt,
             const float* __restrict__ Arl,
             const float* __restrict__ Aimp,
             float2* __restrict__ states) {
    int g = blockIdx.x * blockDim.x + threadIdx.x;   // [C * BH)
    int h = g % H_SZ;
    int b = (g / H_SZ) % B_SZ;
    int c = g / BH;

    float dt = __expf(log_dt[h]);
    float wr[NM], wi[NM];
#pragma unroll
    for (int n = 0; n < NM; ++n) {
        float ar  = -__expf(Arl[h * NM + n]);
        float ai  = Aimp[h * NM + n];
        float er  = __expf(ar * dt);
        float ang = ai * dt;
        wr[n] = er * __cosf(ang);
        wi[n] = er * __sinf(ang);
    }

    float sr[NM], si[NM];
#pragma unroll
    for (int n = 0; n < NM; ++n) { sr[n] = 0.f; si[n] = 0.f; }

    const float* xp = x + (size_t)c * LC * BH + b * H_SZ + h;

    constexpr int BT = 8;
    float buf[BT], nxt[BT];
#pragma unroll
    for (int i = 0; i < BT; ++i) buf[i] = xp[(size_t)i * BH];

#pragma unroll
    for (int tb = 0; tb < LC / BT; ++tb) {
        if (tb + 1 < LC / BT) {
#pragma unroll
            for (int i = 0; i < BT; ++i)
                nxt[i] = xp[(size_t)((tb + 1) * BT + i) * BH];
        }
#pragma unroll
        for (int i = 0; i < BT; ++i) {
            float xv = buf[i];
#pragma unroll
            for (int n = 0; n < NM; ++n) {
                float nsr = fmaf(wr[n], sr[n], fmaf(-wi[n], si[n], xv));
                float nsi = fmaf(wr[n], si[n], wi[n] * sr[n]);
                sr[n] = nsr; si[n] = nsi;
            }
        }
#pragma unroll
        for (int i = 0; i < BT; ++i) buf[i] = nxt[i];
    }

    // states[c][b][n][h]
    float2* st = states + (size_t)(c * B_SZ + b) * NM * H_SZ + h;
#pragma unroll
    for (int n = 0; n < NM; ++n) st[(size_t)n * H_SZ] = make_float2(sr[n], si[n]);
}

// 128-thread blocks: BH*NM = 32768 threads -> 256 blocks, one per CU.
// BT=16: 16 outstanding 512B wave-transactions per wave; the chunk walk is
// stride 256KB so hits are cross-XCD L2/L3 (~400cy) — needs the depth.
template <int CC, int LC>
__global__ void __launch_bounds__(128, 4)
k2_carry_scan(const float* __restrict__ log_dt,
              const float* __restrict__ Arl,
              const float* __restrict__ Aimp,
              float2* __restrict__ states) {
    int g = blockIdx.x * blockDim.x + threadIdx.x;   // [BH * NM), h fastest
    int h = g % H_SZ;
    int n = (g / H_SZ) % NM;
    int b = g / (H_SZ * NM);

    float dt  = __expf(log_dt[h]);
    float Are = -__expf(Arl[h * NM + n]);
    float Aim = Aimp[h * NM + n];
    // w^LC = exp(dt*A*LC)
    float er  = __expf(Are * dt * (float)LC);
    float ang = Aim * dt * (float)LC;
    float wr = er * __cosf(ang), wi = er * __sinf(ang);

    const size_t stride = (size_t)B_SZ * NM * H_SZ;  // chunk-to-chunk
    float2* base = states + ((size_t)b * NM + n) * H_SZ + h;

    float cr = 0.f, ci = 0.f;
    constexpr int BT = 16;
    float2 buf[BT], nxt[BT];
#pragma unroll
    for (int i = 0; i < BT; ++i) buf[i] = base[(size_t)i * stride];

#pragma unroll
    for (int cb = 0; cb < CC / BT; ++cb) {
        if (cb + 1 < CC / BT) {
#pragma unroll
            for (int i = 0; i < BT; ++i)
                nxt[i] = base[(size_t)((cb + 1) * BT + i) * stride];
        }
#pragma unroll
        for (int i = 0; i < BT; ++i) {
            int c = cb * BT + i;
            base[(size_t)c * stride] = make_float2(cr, ci);  // exclusive carry
            float ncr = fmaf(wr, cr, fmaf(-wi, ci, buf[i].x));
            float nci = fmaf(wr, ci, fmaf(wi, cr, buf[i].y));
            cr = ncr; ci = nci;
        }
#pragma unroll
        for (int i = 0; i < BT; ++i) buf[i] = nxt[i];
    }
}

template <int LC>
__global__ void __launch_bounds__(256, 4)
k3_output(const float* __restrict__ x,
          const float* __restrict__ Dp,
          const float* __restrict__ log_dt,
          const float* __restrict__ Arl,
          const float* __restrict__ Aimp,
          const float* __restrict__ Crep,
          const float* __restrict__ Cimp,
          const float2* __restrict__ states,
          float* __restrict__ out) {
    int g = blockIdx.x * blockDim.x + threadIdx.x;   // [C * BH)
    int h = g % H_SZ;
    int b = (g / H_SZ) % B_SZ;
    int c = g / BH;

    float dt = __expf(log_dt[h]);
    float wr[NM], wi[NM], cdr[NM], cdi[NM];
#pragma unroll
    for (int n = 0; n < NM; ++n) {
        float ar  = -__expf(Arl[h * NM + n]);
        float ai  = Aimp[h * NM + n];
        float er  = __expf(ar * dt);
        float ang = ai * dt;
        float wrn = er * __cosf(ang);
        float win = er * __sinf(ang);
        wr[n] = wrn; wi[n] = win;
        // Cd = (Cre + i*Cim) * (w - 1) / A  (divide via conj(A)/|A|^2)
        float inv = 1.0f / (ar * ar + ai * ai);
        float tr = ((wrn - 1.f) * ar + win * ai) * inv;
        float ti = (win * ar - (wrn - 1.f) * ai) * inv;
        float Cre = Crep[h * NM + n], Cim = Cimp[h * NM + n];
        cdr[n] = Cre * tr - Cim * ti;
        cdi[n] = Cre * ti + Cim * tr;
    }

    // carry-in: states[c][b][n][h]
    const float2* st = states + (size_t)(c * B_SZ + b) * NM * H_SZ + h;
    float sr[NM], si[NM];
#pragma unroll
    for (int n = 0; n < NM; ++n) {
        float2 v = st[(size_t)n * H_SZ];
        sr[n] = v.x; si[n] = v.y;
    }

    float Dv = Dp[h];
    const float* xp = x + (size_t)c * LC * BH + b * H_SZ + h;
    float* op = out + (size_t)c * LC * BH + b * H_SZ + h;

    constexpr int BT = 8;
    float buf[BT], nxt[BT];
#pragma unroll
    for (int i = 0; i < BT; ++i) buf[i] = xp[(size_t)i * BH];

#pragma unroll
    for (int tb = 0; tb < LC / BT; ++tb) {
        if (tb + 1 < LC / BT) {
#pragma unroll
            for (int i = 0; i < BT; ++i)
                nxt[i] = xp[(size_t)((tb + 1) * BT + i) * BH];
        }
#pragma unroll
        for (int i = 0; i < BT; ++i) {
            float xv = buf[i];
            float y = 0.f;
#pragma unroll
            for (int n = 0; n < NM; ++n) {
                float nsr = fmaf(wr[n], sr[n], fmaf(-wi[n], si[n], xv));
                float nsi = fmaf(wr[n], si[n], wi[n] * sr[n]);
                sr[n] = nsr; si[n] = nsi;
                y = fmaf(cdr[n], nsr, y);
                y = fmaf(-cdi[n], nsi, y);
            }
            float ov = fmaf(Dv, xv, 2.0f * y);
            __builtin_nontemporal_store(ov, op + (size_t)(tb * BT + i) * BH);
        }
#pragma unroll
        for (int i = 0; i < BT; ++i) buf[i] = nxt[i];
    }
}

extern "C" void kernel_launch(void* const* d_in, const int* in_sizes, int n_in,
                              void* d_out, int out_size, void* d_ws, size_t ws_size,
                              hipStream_t stream) {
    const float* x      = (const float*)d_in[0];
    const float* Dp     = (const float*)d_in[1];
    const float* log_dt = (const float*)d_in[2];
    const float* Arl    = (const float*)d_in[3];
    const float* Aimp   = (const float*)d_in[4];
    const float* Cre    = (const float*)d_in[5];
    const float* Cim    = (const float*)d_in[6];
    float* out = (float*)d_out;
    float2* states = (float2*)d_ws;

    const size_t need64 = (size_t)64 * BH * NM * sizeof(float2);   // 16.8 MB

    if (ws_size >= need64) {
        constexpr int C = 64, LC = T_LEN / 64;      // LC = 64
        int total1 = C * BH;                        // 262144 threads
        k1_chunk_end<LC><<<total1 / 256, 256, 0, stream>>>(x, log_dt, Arl, Aimp, states);
        int total2 = BH * NM;                       // 32768 threads, 128/block
        k2_carry_scan<C, LC><<<total2 / 128, 128, 0, stream>>>(log_dt, Arl, Aimp, states);
        k3_output<LC><<<total1 / 256, 256, 0, stream>>>(x, Dp, log_dt, Arl, Aimp,
                                                        Cre, Cim, states, out);
    } else {
        constexpr int C = 32, LC = T_LEN / 32;      // LC = 128 (8.4 MB states)
        int total1 = C * BH;
        k1_chunk_end<LC><<<total1 / 256, 256, 0, stream>>>(x, log_dt, Arl, Aimp, states);
        int total2 = BH * NM;
        k2_carry_scan<C, LC><<<total2 / 128, 128, 0, stream>>>(log_dt, Arl, Aimp, states);
        k3_output<LC><<<total1 / 256, 256, 0, stream>>>(x, Dp, log_dt, Arl, Aimp,
                                                        Cre, Cim, states, out);
    }
}